// Round 5
// baseline (537.008 us; speedup 1.0000x reference)
//
#include <hip/hip_runtime.h>
#include <math.h>

#define NNODES   50000
#define NFEAT    512
#define NCLASS   256
#define NEG_SLOPE 0.2f
#define MPAD     50048   // 391 * 128

typedef __attribute__((ext_vector_type(8))) short short8;
typedef __attribute__((ext_vector_type(4))) float floatx4;

__device__ __forceinline__ unsigned short f2bf(float f) {
    unsigned u = __builtin_bit_cast(unsigned, f);
    u += 0x7fffu + ((u >> 16) & 1u);          // RNE
    return (unsigned short)(u >> 16);
}
__device__ __forceinline__ float bf2f(unsigned short s) {
    return __builtin_bit_cast(float, ((unsigned)s) << 16);
}
__device__ __forceinline__ float bf2f_lo(unsigned u) {
    return __builtin_bit_cast(float, u << 16);
}
__device__ __forceinline__ float bf2f_hi(unsigned u) {
    return __builtin_bit_cast(float, u & 0xffff0000u);
}
__device__ __forceinline__ unsigned pack_bf16_rh(float lo, float hi) {
    const unsigned ulo = __builtin_bit_cast(unsigned, lo) + 0x8000u;
    const unsigned uhi = __builtin_bit_cast(unsigned, hi) + 0x8000u;
    return __builtin_amdgcn_perm(uhi, ulo, 0x07060302);
}

// ---------------------------------------------------------------------------
// Init: W -> Wt bf16 transposed; zero {s_row, s_col, deg, cursor, rsum} (5*M).
// ---------------------------------------------------------------------------
__global__ __launch_bounds__(256) void init_kernel(const float* __restrict__ W,
                                                   unsigned short* __restrict__ Wt,
                                                   int* __restrict__ zero5, int zn) {
    const int i = blockIdx.x * 256 + threadIdx.x;     // 0..131071
    const int n = i >> 9;
    const int k = i & 511;
    Wt[i] = f2bf(W[(size_t)k * NCLASS + n]);
    for (int j = i; j < zn; j += 131072) zero5[j] = 0;
}

// ---------------------------------------------------------------------------
// MFMA GEMM, fused A fp32->bf16 conversion, fused s_row/s_col dot products.
// Output written in FEATURE-SLICED layout: hbs[slice][node][32], slice=f>>5.
// ---------------------------------------------------------------------------
__global__ __launch_bounds__(256) void gemm_mfma_kernel(const float* __restrict__ x,
                                                        const unsigned short* __restrict__ Wt,
                                                        unsigned short* __restrict__ hbs,
                                                        const float* __restrict__ a,
                                                        float* __restrict__ s_row,
                                                        float* __restrict__ s_col, int M) {
    __shared__ short As[128 * 32];
    __shared__ short Bs[128 * 32];
    __shared__ short Cs[64 * 132];

    const int tid  = threadIdx.x;
    const int w    = tid >> 6;
    const int lane = tid & 63;
    const int rowbase = blockIdx.x * 128;
    const int nbase   = blockIdx.y * 128;

    const int wm = w & 1;
    const int wn = w >> 1;
    const int srow = (lane >> 2);
    const int skq  = (lane & 3) << 3;
    const int fm = lane & 15;
    const int fq = lane >> 4;

    floatx4 acc[4][4];
#pragma unroll
    for (int i = 0; i < 4; ++i)
#pragma unroll
        for (int j = 0; j < 4; ++j)
            acc[i][j] = (floatx4){0.f, 0.f, 0.f, 0.f};

    for (int k0 = 0; k0 < NFEAT; k0 += 32) {
#pragma unroll
        for (int t = 0; t < 2; ++t) {
            const int seg = w * 2 + t;
            const int rr  = seg * 16 + srow;
            __builtin_amdgcn_global_load_lds(
                (const __attribute__((address_space(1))) void*)(Wt + (size_t)(nbase + rr) * NFEAT + k0 + skq),
                (__attribute__((address_space(3))) void*)(Bs + seg * 512), 16, 0, 0);
            const int ar = min(rowbase + rr, M - 1);
            const float4* xp = (const float4*)&x[(size_t)ar * NFEAT + k0 + skq];
            const float4 u0 = xp[0];
            const float4 u1 = xp[1];
            uint4 o;
            o.x = pack_bf16_rh(u0.x, u0.y);
            o.y = pack_bf16_rh(u0.z, u0.w);
            o.z = pack_bf16_rh(u1.x, u1.y);
            o.w = pack_bf16_rh(u1.z, u1.w);
            *(uint4*)&As[rr * 32 + skq] = o;
        }
        __syncthreads();

        short8 af[4], bfr[4];
#pragma unroll
        for (int mt = 0; mt < 4; ++mt)
            af[mt] = *(const short8*)&As[(wm * 64 + mt * 16 + fm) * 32 + fq * 8];
#pragma unroll
        for (int nt = 0; nt < 4; ++nt)
            bfr[nt] = *(const short8*)&Bs[(wn * 64 + nt * 16 + fm) * 32 + fq * 8];

#pragma unroll
        for (int mt = 0; mt < 4; ++mt)
#pragma unroll
            for (int nt = 0; nt < 4; ++nt)
                acc[mt][nt] = __builtin_amdgcn_mfma_f32_16x16x32_bf16(af[mt], bfr[nt], acc[mt][nt], 0, 0, 0);

        __syncthreads();
    }

    for (int p = 0; p < 2; ++p) {
        if (p) __syncthreads();
        if (wm == p) {
#pragma unroll
            for (int mt = 0; mt < 4; ++mt)
#pragma unroll
                for (int nt = 0; nt < 4; ++nt)
#pragma unroll
                    for (int r = 0; r < 4; ++r)
                        Cs[(mt * 16 + fq * 4 + r) * 132 + wn * 64 + nt * 16 + fm] =
                            (short)f2bf(acc[mt][nt][r]);
        }
        __syncthreads();
#pragma unroll
        for (int k = 0; k < 8; ++k) {
            const int idx = tid + k * 256;
            const int lrow = idx >> 5;
            const int c4 = (idx & 31) << 2;
            const int grow = rowbase + p * 64 + lrow;
            const uint2 vv = *(const uint2*)&Cs[lrow * 132 + c4];
            const float f0 = bf2f_lo(vv.x), f1 = bf2f_hi(vv.x);
            const float f2 = bf2f_lo(vv.y), f3 = bf2f_hi(vv.y);
            const int col = nbase + c4;
            const float4 A1 = *(const float4*)&a[col];
            const float4 A2 = *(const float4*)&a[NCLASS + col];
            float p1 = f0 * A1.x + f1 * A1.y + f2 * A1.z + f3 * A1.w;
            float p2 = f0 * A2.x + f1 * A2.y + f2 * A2.z + f3 * A2.w;
#pragma unroll
            for (int off = 1; off < 32; off <<= 1) {
                p1 += __shfl_xor(p1, off);
                p2 += __shfl_xor(p2, off);
            }
            if (grow < M) {
                // feature-sliced store: slice = col>>5, within = col&31
                *(uint2*)&hbs[((size_t)(col >> 5) * M + grow) * 32 + (col & 31)] = vv;
                if ((lane & 31) == 0) {
                    atomicAdd(&s_row[grow], p1);
                    atomicAdd(&s_col[grow], p2);
                }
            }
        }
    }
}

// ---------------------------------------------------------------------------
// CSR build
// ---------------------------------------------------------------------------
__global__ __launch_bounds__(256) void hist_kernel(const int* __restrict__ row,
                                                   int* __restrict__ deg, int e) {
    const int i = blockIdx.x * 256 + threadIdx.x;
    if (i < e) atomicAdd(&deg[row[i]], 1);
}

__global__ __launch_bounds__(256) void scan1_kernel(const int* __restrict__ deg,
                                                    int* __restrict__ tmp,
                                                    int* __restrict__ blocksum, int n) {
    __shared__ int buf[256];
    const int i = blockIdx.x * 256 + threadIdx.x;
    const int t = threadIdx.x;
    buf[t] = (i < n) ? deg[i] : 0;
    __syncthreads();
#pragma unroll
    for (int off = 1; off < 256; off <<= 1) {
        const int u = (t >= off) ? buf[t - off] : 0;
        __syncthreads();
        buf[t] += u;
        __syncthreads();
    }
    if (i < n) tmp[i] = buf[t];
    if (t == 255) blocksum[blockIdx.x] = buf[255];
}

__global__ __launch_bounds__(256) void scan3_kernel(const int* __restrict__ tmp,
                                                    const int* __restrict__ blocksum,
                                                    int* __restrict__ rowstart, int n, int nb) {
    __shared__ int buf[256];
    const int t = threadIdx.x;
    buf[t] = (t < nb) ? blocksum[t] : 0;
    __syncthreads();
#pragma unroll
    for (int off = 1; off < 256; off <<= 1) {
        const int u = (t >= off) ? buf[t - off] : 0;
        __syncthreads();
        buf[t] += u;
        __syncthreads();
    }
    const int boff = (blockIdx.x == 0) ? 0 : buf[blockIdx.x - 1];
    const int i = blockIdx.x * 256 + t;
    if (i < n) rowstart[i + 1] = tmp[i] + boff;
    if (i == 0) rowstart[0] = 0;
}

// scatter + e computation + rowsum accumulation
__global__ __launch_bounds__(256) void scatter_kernel(const int* __restrict__ row,
                                                      const int* __restrict__ col,
                                                      const float* __restrict__ s_row,
                                                      const float* __restrict__ s_col,
                                                      const int* __restrict__ rowstart,
                                                      int* __restrict__ cursor,
                                                      float* __restrict__ rsum,
                                                      int2* __restrict__ sorted_ce, int e) {
    const int i = blockIdx.x * 256 + threadIdx.x;
    if (i >= e) return;
    const int r = row[i];
    const int c = col[i];
    const float logit = s_row[r] + s_col[c];
    const float lr = logit > 0.f ? logit : NEG_SLOPE * logit;
    const float ew = __expf(-lr);
    atomicAdd(&rsum[r], ew);
    const int pos = atomicAdd(&cursor[r], 1);
    int2 v;
    v.x = c;
    v.y = __builtin_bit_cast(int, ew);
    sorted_ce[rowstart[r] + pos] = v;
}

// ---------------------------------------------------------------------------
// Sliced aggregation: block b -> slice (b&7), 32-row chunk (b>>3).
// Wave handles 8 rows; lanes 0-31 edge j, lanes 32-63 edge j+1; f = lane&31.
// Gather working set per slice = 3.2 MB -> L2-resident with %8 XCD mapping.
// Writes raw weighted sums as bf16 to partial[slice][node][32].
// ---------------------------------------------------------------------------
__global__ __launch_bounds__(256) void aggslice_kernel(const unsigned short* __restrict__ hbs,
                                                       const int2* __restrict__ sorted_ce,
                                                       const int* __restrict__ rowstart,
                                                       unsigned short* __restrict__ partial,
                                                       int n) {
    const int s     = blockIdx.x & 7;
    const int chunk = blockIdx.x >> 3;
    const int w     = threadIdx.x >> 6;
    const int lane  = threadIdx.x & 63;
    const int eh    = lane >> 5;        // which edge of the pair
    const int f     = lane & 31;        // feature within slice
    const unsigned short* hs = hbs + (size_t)s * n * 32;
    unsigned short* ps = partial + (size_t)s * n * 32;

    const int r0 = chunk * 32 + w * 8;
#pragma unroll 1
    for (int ri = 0; ri < 8; ++ri) {
        const int r = r0 + ri;
        if (r >= n) return;
        const int jb = rowstart[r];
        const int je = rowstart[r + 1];
        float acc = 0.f;
        int j = jb;
        for (; j + 3 < je; j += 4) {
            const int2 ra = sorted_ce[j + eh];
            const int2 rb = sorted_ce[j + 2 + eh];
            const float ha = bf2f(hs[(size_t)ra.x * 32 + f]);
            const float hbv = bf2f(hs[(size_t)rb.x * 32 + f]);
            acc += __builtin_bit_cast(float, ra.y) * ha
                 + __builtin_bit_cast(float, rb.y) * hbv;
        }
        for (; j < je; j += 2) {
            const int jj = j + eh;
            const bool ok = jj < je;
            const int2 rc = ok ? sorted_ce[jj] : make_int2(0, 0);
            const float hv = bf2f(hs[(size_t)rc.x * 32 + f]);
            acc += (ok ? __builtin_bit_cast(float, rc.y) : 0.f) * hv;
        }
        acc += __shfl_xor(acc, 32);
        if (eh == 0)
            ps[(size_t)r * 32 + f] = f2bf(acc);
    }
}

// ---------------------------------------------------------------------------
// Final pass: div by rowsum, elu, log_softmax. One wave per row.
// lane l covers feats [4l, 4l+4): slice = l>>3, within = (4l)&31.
// ---------------------------------------------------------------------------
__global__ __launch_bounds__(256) void softmax_kernel(const unsigned short* __restrict__ partial,
                                                      const float* __restrict__ rsum,
                                                      float* __restrict__ out, int n) {
    const int wave = (int)((blockIdx.x * (size_t)blockDim.x + threadIdx.x) >> 6);
    const int lane = threadIdx.x & 63;
    if (wave >= n) return;
    const int r = wave;
    const int fb = lane << 2;
    const ushort4 pv = *(const ushort4*)&partial[((size_t)(fb >> 5) * n + r) * 32 + (fb & 31)];
    const float inv = 1.f / rsum[r];
    float v[4] = {bf2f(pv.x) * inv, bf2f(pv.y) * inv, bf2f(pv.z) * inv, bf2f(pv.w) * inv};
#pragma unroll
    for (int i = 0; i < 4; ++i)
        v[i] = v[i] > 0.f ? v[i] : __expf(v[i]) - 1.f;

    float m = fmaxf(fmaxf(v[0], v[1]), fmaxf(v[2], v[3]));
#pragma unroll
    for (int off = 32; off > 0; off >>= 1) m = fmaxf(m, __shfl_xor(m, off));
    float s = 0.f;
#pragma unroll
    for (int i = 0; i < 4; ++i) s += __expf(v[i] - m);
#pragma unroll
    for (int off = 32; off > 0; off >>= 1) s += __shfl_xor(s, off);
    const float lse = m + __logf(s);

    float4 o = make_float4(v[0] - lse, v[1] - lse, v[2] - lse, v[3] - lse);
    *(float4*)&out[(size_t)r * NCLASS + fb] = o;
}

// ---------------------------------------------------------------------------
extern "C" void kernel_launch(void* const* d_in, const int* in_sizes, int n_in,
                              void* d_out, int out_size, void* d_ws, size_t ws_size,
                              hipStream_t stream) {
    const float* x  = (const float*)d_in[0];
    const float* W  = (const float*)d_in[1];
    const float* a  = (const float*)d_in[2];
    const int* edge = (const int*)d_in[3];
    float* out = (float*)d_out;

    const int M = in_sizes[0] / NFEAT;         // 50000
    const int E = in_sizes[3] / 2;             // 850000
    const int* row = edge;
    const int* col = edge + E;

    char* ws = (char*)d_ws;
    size_t off = 0;
    auto carve = [&](size_t bytes) -> char* {
        char* p = ws + off;
        off = (off + bytes + 255) & ~(size_t)255;
        return p;
    };
    unsigned short* Wt = (unsigned short*)carve((size_t)NCLASS * NFEAT * sizeof(short));
    unsigned short* hbs = (unsigned short*)carve((size_t)M * NCLASS * sizeof(short));     // 25.6MB sliced
    unsigned short* partial = (unsigned short*)carve((size_t)M * NCLASS * sizeof(short)); // 25.6MB sliced
    int*   zero5    = (int*)carve((size_t)5 * M * sizeof(int));
    float* s_row    = (float*)zero5;
    float* s_col    = (float*)(zero5 + M);
    int*   deg      = zero5 + 2 * M;
    int*   cursor   = zero5 + 3 * M;
    float* rsum     = (float*)(zero5 + 4 * M);
    int*   rowstart = (int*)carve((size_t)(M + 1) * sizeof(int));
    int*   tmp_scan = (int*)carve((size_t)M * sizeof(int));
    int*   blocksum = (int*)carve((size_t)256 * sizeof(int));
    int2*  sorted_ce = (int2*)carve((size_t)E * sizeof(int2));

    init_kernel<<<512, 256, 0, stream>>>(W, Wt, zero5, 5 * M);

    dim3 ggrid(MPAD / 128, NCLASS / 128);
    gemm_mfma_kernel<<<ggrid, 256, 0, stream>>>(x, Wt, hbs, a, s_row, s_col, M);

    const int nb1 = (M + 255) / 256;   // 196
    hist_kernel<<<(E + 255) / 256, 256, 0, stream>>>(row, deg, E);
    scan1_kernel<<<nb1, 256, 0, stream>>>(deg, tmp_scan, blocksum, M);
    scan3_kernel<<<nb1, 256, 0, stream>>>(tmp_scan, blocksum, rowstart, M, nb1);
    scatter_kernel<<<(E + 255) / 256, 256, 0, stream>>>(row, col, s_row, s_col,
                                                        rowstart, cursor, rsum, sorted_ce, E);

    const int nchunks = (M + 31) / 32;   // 1563
    aggslice_kernel<<<8 * nchunks, 256, 0, stream>>>(hbs, sorted_ce, rowstart, partial, M);

    softmax_kernel<<<(M + 3) / 4, 256, 0, stream>>>(partial, rsum, out, M);
}

// Round 6
// 320.895 us; speedup vs baseline: 1.6735x; 1.6735x over previous
//
#include <hip/hip_runtime.h>
#include <math.h>

#define NNODES   50000
#define NFEAT    512
#define NCLASS   256
#define NEG_SLOPE 0.2f
#define MPAD     50048   // 391 * 128
#define GBLK     391

typedef __attribute__((ext_vector_type(8))) short short8;
typedef __attribute__((ext_vector_type(4))) float floatx4;

__device__ __forceinline__ unsigned short f2bf(float f) {
    unsigned u = __builtin_bit_cast(unsigned, f);
    u += 0x7fffu + ((u >> 16) & 1u);          // RNE
    return (unsigned short)(u >> 16);
}
__device__ __forceinline__ float bf2f(unsigned short s) {
    return __builtin_bit_cast(float, ((unsigned)s) << 16);
}
__device__ __forceinline__ float bf2f_lo(unsigned u) {
    return __builtin_bit_cast(float, u << 16);
}
__device__ __forceinline__ float bf2f_hi(unsigned u) {
    return __builtin_bit_cast(float, u & 0xffff0000u);
}
// pack two floats -> (bf16(lo) | bf16(hi)<<16), round-half-away
__device__ __forceinline__ unsigned pack_bf16_rh(float lo, float hi) {
    const unsigned ulo = __builtin_bit_cast(unsigned, lo) + 0x8000u;
    const unsigned uhi = __builtin_bit_cast(unsigned, hi) + 0x8000u;
    return __builtin_amdgcn_perm(uhi, ulo, 0x07060302);
}

#if __has_builtin(__builtin_amdgcn_fdot2_f32_bf16)
#define HAVE_DOT2 1
typedef __attribute__((ext_vector_type(2))) __bf16 bfx2;
__device__ __forceinline__ float dot2bf(unsigned hpair, unsigned epair, float acc) {
    return __builtin_amdgcn_fdot2_f32_bf16(__builtin_bit_cast(bfx2, hpair),
                                           __builtin_bit_cast(bfx2, epair), acc, false);
}
#endif

// ---------------------------------------------------------------------------
// Init: W [512][256] fp32 -> Wt [256][512] bf16 transposed; zero deg+cursor.
// ---------------------------------------------------------------------------
__global__ __launch_bounds__(256) void init_kernel(const float* __restrict__ W,
                                                   unsigned short* __restrict__ Wt,
                                                   int* __restrict__ zero2, int zn) {
    const int i = blockIdx.x * 256 + threadIdx.x;     // 0..131071
    const int n = i >> 9;
    const int k = i & 511;
    Wt[i] = f2bf(W[(size_t)k * NCLASS + n]);
    for (int j = i; j < zn; j += 131072) zero2[j] = 0;
}

// ---------------------------------------------------------------------------
// MFMA GEMM, single pass over x: 128x256 block tile (full N), 4 waves as
// 2x2 over (64 rows x 128 cols), acc 4x8. A: fp32->bf16 in-register staging.
// B: global_load_lds. Epilogue: LDS-staged coalesced stores + exact per-row
// s_row/s_col (plain stores, no atomics). Tail: grid-stride edge histogram.
// ---------------------------------------------------------------------------
__global__ __launch_bounds__(256, 2) void gemm_mfma_kernel(const float* __restrict__ x,
                                                           const unsigned short* __restrict__ Wt,
                                                           unsigned short* __restrict__ hb,
                                                           const float* __restrict__ a,
                                                           float* __restrict__ s_row,
                                                           float* __restrict__ s_col,
                                                           const int* __restrict__ erow,
                                                           int* __restrict__ deg,
                                                           int M, int E) {
    __shared__ union {
        struct { short As[128 * 32]; short Bs[256 * 32]; } k;   // 24KB
        short Cs[32 * 260];                                     // 16.6KB (epilogue)
    } u;

    const int tid  = threadIdx.x;
    const int w    = tid >> 6;
    const int lane = tid & 63;
    const int rowbase = blockIdx.x * 128;

    const int wm = w & 1;     // 64-row half
    const int wn = w >> 1;    // 128-col half
    const int srow = lane >> 2;
    const int skq  = (lane & 3) << 3;
    const int fm = lane & 15;
    const int fq = lane >> 4;

    floatx4 acc[4][8];
#pragma unroll
    for (int i = 0; i < 4; ++i)
#pragma unroll
        for (int j = 0; j < 8; ++j)
            acc[i][j] = (floatx4){0.f, 0.f, 0.f, 0.f};

    for (int k0 = 0; k0 < NFEAT; k0 += 32) {
        // B: 16 segs of 16 n-rows; wave w stages segs 4w..4w+3
#pragma unroll
        for (int t = 0; t < 4; ++t) {
            const int seg = w * 4 + t;
            const int nr  = seg * 16 + srow;
            __builtin_amdgcn_global_load_lds(
                (const __attribute__((address_space(1))) void*)(Wt + (size_t)nr * NFEAT + k0 + skq),
                (__attribute__((address_space(3))) void*)(u.k.Bs + seg * 512), 16, 0, 0);
        }
        // A: 8 segs of 16 rows; wave w stages segs 2w, 2w+1 (fp32->bf16)
#pragma unroll
        for (int t = 0; t < 2; ++t) {
            const int seg = w * 2 + t;
            const int rr  = seg * 16 + srow;
            const int ar  = min(rowbase + rr, M - 1);
            const float4* xp = (const float4*)&x[(size_t)ar * NFEAT + k0 + skq];
            const float4 u0 = xp[0];
            const float4 u1 = xp[1];
            uint4 o;
            o.x = pack_bf16_rh(u0.x, u0.y);
            o.y = pack_bf16_rh(u0.z, u0.w);
            o.z = pack_bf16_rh(u1.x, u1.y);
            o.w = pack_bf16_rh(u1.z, u1.w);
            *(uint4*)&u.k.As[rr * 32 + skq] = o;
        }
        __syncthreads();

        short8 af[4];
#pragma unroll
        for (int mt = 0; mt < 4; ++mt)
            af[mt] = *(const short8*)&u.k.As[(wm * 64 + mt * 16 + fm) * 32 + fq * 8];
#pragma unroll
        for (int nt = 0; nt < 8; ++nt) {
            const short8 bfr = *(const short8*)&u.k.Bs[(wn * 128 + nt * 16 + fm) * 32 + fq * 8];
#pragma unroll
            for (int mt = 0; mt < 4; ++mt)
                acc[mt][nt] = __builtin_amdgcn_mfma_f32_16x16x32_bf16(af[mt], bfr, acc[mt][nt], 0, 0, 0);
        }
        __syncthreads();
    }

    // Epilogue: 4 passes of 32 rows through Cs (stride 260).
#pragma unroll
    for (int p = 0; p < 4; ++p) {
        __syncthreads();
        if ((w & 1) == (p >> 1)) {
#pragma unroll
            for (int mt2 = 0; mt2 < 2; ++mt2) {
                const int mt = (p & 1) * 2 + mt2;
#pragma unroll
                for (int nt = 0; nt < 8; ++nt)
#pragma unroll
                    for (int r = 0; r < 4; ++r)
                        u.Cs[(mt2 * 16 + fq * 4 + r) * 260 + wn * 128 + nt * 16 + fm] =
                            (short)f2bf(acc[mt][nt][r]);
            }
        }
        __syncthreads();
        // 32 rows x 256 cols: 2048 uint2 chunks; one wave handles one row/iter
#pragma unroll
        for (int k = 0; k < 8; ++k) {
            const int idx = tid + k * 256;
            const int lrow = idx >> 6;
            const int c4 = (idx & 63) << 2;
            const int grow = rowbase + p * 32 + lrow;
            const uint2 vv = *(const uint2*)&u.Cs[lrow * 260 + c4];
            const float f0 = bf2f_lo(vv.x), f1 = bf2f_hi(vv.x);
            const float f2 = bf2f_lo(vv.y), f3 = bf2f_hi(vv.y);
            const float4 A1 = *(const float4*)&a[c4];
            const float4 A2 = *(const float4*)&a[NCLASS + c4];
            float p1 = f0 * A1.x + f1 * A1.y + f2 * A1.z + f3 * A1.w;
            float p2 = f0 * A2.x + f1 * A2.y + f2 * A2.z + f3 * A2.w;
#pragma unroll
            for (int off = 1; off < 64; off <<= 1) {
                p1 += __shfl_xor(p1, off);
                p2 += __shfl_xor(p2, off);
            }
            if (grow < M) {
                *(uint2*)&hb[(size_t)grow * NCLASS + c4] = vv;
                if (lane == 0) {
                    s_row[grow] = p1;
                    s_col[grow] = p2;
                }
            }
        }
    }

    // Fused histogram tail (deg zeroed by init, which ran before this kernel)
    const int gtid = blockIdx.x * 256 + tid;
    for (int i = gtid; i < E; i += GBLK * 256)
        atomicAdd(&deg[erow[i]], 1);
}

// ---------------------------------------------------------------------------
// Two-level scan
// ---------------------------------------------------------------------------
__global__ __launch_bounds__(256) void scan1_kernel(const int* __restrict__ deg,
                                                    int* __restrict__ tmp,
                                                    int* __restrict__ blocksum, int n) {
    __shared__ int buf[256];
    const int i = blockIdx.x * 256 + threadIdx.x;
    const int t = threadIdx.x;
    buf[t] = (i < n) ? deg[i] : 0;
    __syncthreads();
#pragma unroll
    for (int off = 1; off < 256; off <<= 1) {
        const int uv = (t >= off) ? buf[t - off] : 0;
        __syncthreads();
        buf[t] += uv;
        __syncthreads();
    }
    if (i < n) tmp[i] = buf[t];
    if (t == 255) blocksum[blockIdx.x] = buf[255];
}

__global__ __launch_bounds__(256) void scan3_kernel(const int* __restrict__ tmp,
                                                    const int* __restrict__ blocksum,
                                                    int* __restrict__ rowstart, int n, int nb) {
    __shared__ int buf[256];
    const int t = threadIdx.x;
    buf[t] = (t < nb) ? blocksum[t] : 0;
    __syncthreads();
#pragma unroll
    for (int off = 1; off < 256; off <<= 1) {
        const int uv = (t >= off) ? buf[t - off] : 0;
        __syncthreads();
        buf[t] += uv;
        __syncthreads();
    }
    const int boff = (blockIdx.x == 0) ? 0 : buf[blockIdx.x - 1];
    const int i = blockIdx.x * 256 + t;
    if (i < n) rowstart[i + 1] = tmp[i] + boff;
    if (i == 0) rowstart[0] = 0;
}

// ---------------------------------------------------------------------------
// Scatter + fused attention weight: store {col, e} per edge, row-grouped.
// ---------------------------------------------------------------------------
__global__ __launch_bounds__(256) void scatter_kernel(const int* __restrict__ row,
                                                      const int* __restrict__ col,
                                                      const float* __restrict__ s_row,
                                                      const float* __restrict__ s_col,
                                                      const int* __restrict__ rowstart,
                                                      int* __restrict__ cursor,
                                                      int2* __restrict__ sorted_ce, int e) {
    const int i = blockIdx.x * 256 + threadIdx.x;
    if (i >= e) return;
    const int r = row[i];
    const int c = col[i];
    const float logit = s_row[r] + s_col[c];
    const float lr = logit > 0.f ? logit : NEG_SLOPE * logit;
    const float ew = __expf(-lr);
    const int pos = atomicAdd(&cursor[r], 1);
    int2 v;
    v.x = c;
    v.y = __builtin_bit_cast(int, ew);
    sorted_ce[rowstart[r] + pos] = v;
}

// ---------------------------------------------------------------------------
// Aggregation + elu + log_softmax. One wave per row; lane holds 4 features
// (8B gathers). Inner loop: bf16 dot2 pairs (v_dot2_f32_bf16) when available.
// ---------------------------------------------------------------------------
__global__ __launch_bounds__(256) void aggregate_kernel(const unsigned short* __restrict__ hb,
                                                        const int2* __restrict__ sorted_ce,
                                                        const int* __restrict__ rowstart,
                                                        float* __restrict__ out, int n) {
    const int wave = (int)((blockIdx.x * (size_t)blockDim.x + threadIdx.x) >> 6);
    const int lane = threadIdx.x & 63;
    if (wave >= n) return;
    const int r = wave;
    const int jb = rowstart[r];
    const int je = rowstart[r + 1];
    const int fo = lane << 2;

    float rowsum = 0.f;
    int j = jb;

#ifdef HAVE_DOT2
    float ac0 = 0.f, ac1 = 0.f, ac2 = 0.f, ac3 = 0.f;
    for (; j + 3 < je; j += 4) {
        const int2 v0 = sorted_ce[j];
        const int2 v1 = sorted_ce[j + 1];
        const int2 v2 = sorted_ce[j + 2];
        const int2 v3 = sorted_ce[j + 3];
        const uint2 g0 = *(const uint2*)&hb[(size_t)v0.x * NCLASS + fo];
        const uint2 g1 = *(const uint2*)&hb[(size_t)v1.x * NCLASS + fo];
        const uint2 g2 = *(const uint2*)&hb[(size_t)v2.x * NCLASS + fo];
        const uint2 g3 = *(const uint2*)&hb[(size_t)v3.x * NCLASS + fo];
        const float e0 = __builtin_bit_cast(float, v0.y);
        const float e1 = __builtin_bit_cast(float, v1.y);
        const float e2 = __builtin_bit_cast(float, v2.y);
        const float e3 = __builtin_bit_cast(float, v3.y);
        const unsigned ep01 = pack_bf16_rh(e0, e1);
        const unsigned ep23 = pack_bf16_rh(e2, e3);
        rowsum += (e0 + e1) + (e2 + e3);
        ac0 = dot2bf(__builtin_amdgcn_perm(g1.x, g0.x, 0x05040100), ep01, ac0);
        ac1 = dot2bf(__builtin_amdgcn_perm(g1.x, g0.x, 0x07060302), ep01, ac1);
        ac2 = dot2bf(__builtin_amdgcn_perm(g1.y, g0.y, 0x05040100), ep01, ac2);
        ac3 = dot2bf(__builtin_amdgcn_perm(g1.y, g0.y, 0x07060302), ep01, ac3);
        ac0 = dot2bf(__builtin_amdgcn_perm(g3.x, g2.x, 0x05040100), ep23, ac0);
        ac1 = dot2bf(__builtin_amdgcn_perm(g3.x, g2.x, 0x07060302), ep23, ac1);
        ac2 = dot2bf(__builtin_amdgcn_perm(g3.y, g2.y, 0x05040100), ep23, ac2);
        ac3 = dot2bf(__builtin_amdgcn_perm(g3.y, g2.y, 0x07060302), ep23, ac3);
    }
    float4 acc = make_float4(ac0, ac1, ac2, ac3);
#else
    float4 acc = make_float4(0.f, 0.f, 0.f, 0.f);
    for (; j + 3 < je; j += 4) {
        const int2 v0 = sorted_ce[j];
        const int2 v1 = sorted_ce[j + 1];
        const int2 v2 = sorted_ce[j + 2];
        const int2 v3 = sorted_ce[j + 3];
        const uint2 g0 = *(const uint2*)&hb[(size_t)v0.x * NCLASS + fo];
        const uint2 g1 = *(const uint2*)&hb[(size_t)v1.x * NCLASS + fo];
        const uint2 g2 = *(const uint2*)&hb[(size_t)v2.x * NCLASS + fo];
        const uint2 g3 = *(const uint2*)&hb[(size_t)v3.x * NCLASS + fo];
        const float e0 = __builtin_bit_cast(float, v0.y);
        const float e1 = __builtin_bit_cast(float, v1.y);
        const float e2 = __builtin_bit_cast(float, v2.y);
        const float e3 = __builtin_bit_cast(float, v3.y);
        rowsum += (e0 + e1) + (e2 + e3);
        acc.x += e0 * bf2f_lo(g0.x) + e1 * bf2f_lo(g1.x) + e2 * bf2f_lo(g2.x) + e3 * bf2f_lo(g3.x);
        acc.y += e0 * bf2f_hi(g0.x) + e1 * bf2f_hi(g1.x) + e2 * bf2f_hi(g2.x) + e3 * bf2f_hi(g3.x);
        acc.z += e0 * bf2f_lo(g0.y) + e1 * bf2f_lo(g1.y) + e2 * bf2f_lo(g2.y) + e3 * bf2f_lo(g3.y);
        acc.w += e0 * bf2f_hi(g0.y) + e1 * bf2f_hi(g1.y) + e2 * bf2f_hi(g2.y) + e3 * bf2f_hi(g3.y);
    }
#endif
    for (; j < je; ++j) {
        const int2 v = sorted_ce[j];
        const uint2 g = *(const uint2*)&hb[(size_t)v.x * NCLASS + fo];
        const float e = __builtin_bit_cast(float, v.y);
        rowsum += e;
        acc.x += e * bf2f_lo(g.x);
        acc.y += e * bf2f_hi(g.x);
        acc.z += e * bf2f_lo(g.y);
        acc.w += e * bf2f_hi(g.y);
    }

    const float inv = 1.f / rowsum;
    float v[4] = {acc.x * inv, acc.y * inv, acc.z * inv, acc.w * inv};
#pragma unroll
    for (int i = 0; i < 4; ++i)
        v[i] = v[i] > 0.f ? v[i] : __expf(v[i]) - 1.f;

    float m = fmaxf(fmaxf(v[0], v[1]), fmaxf(v[2], v[3]));
#pragma unroll
    for (int off = 32; off > 0; off >>= 1) m = fmaxf(m, __shfl_xor(m, off));
    float s = 0.f;
#pragma unroll
    for (int i = 0; i < 4; ++i) s += __expf(v[i] - m);
#pragma unroll
    for (int off = 32; off > 0; off >>= 1) s += __shfl_xor(s, off);
    const float lse = m + __logf(s);

    float4 o = make_float4(v[0] - lse, v[1] - lse, v[2] - lse, v[3] - lse);
    *(float4*)&out[(size_t)r * NCLASS + fo] = o;
}

// ---------------------------------------------------------------------------
extern "C" void kernel_launch(void* const* d_in, const int* in_sizes, int n_in,
                              void* d_out, int out_size, void* d_ws, size_t ws_size,
                              hipStream_t stream) {
    const float* x  = (const float*)d_in[0];
    const float* W  = (const float*)d_in[1];
    const float* a  = (const float*)d_in[2];
    const int* edge = (const int*)d_in[3];
    float* out = (float*)d_out;

    const int M = in_sizes[0] / NFEAT;         // 50000
    const int E = in_sizes[3] / 2;             // 850000
    const int* row = edge;
    const int* col = edge + E;

    char* ws = (char*)d_ws;
    size_t off = 0;
    auto carve = [&](size_t bytes) -> char* {
        char* p = ws + off;
        off = (off + bytes + 255) & ~(size_t)255;
        return p;
    };
    unsigned short* Wt = (unsigned short*)carve((size_t)NCLASS * NFEAT * sizeof(short));
    unsigned short* hb = (unsigned short*)carve((size_t)M * NCLASS * sizeof(short)); // 25.6MB
    int*   zero2    = (int*)carve((size_t)2 * M * sizeof(int));   // deg, cursor
    int*   deg      = zero2;
    int*   cursor   = zero2 + M;
    float* s_row    = (float*)carve((size_t)M * sizeof(float));
    float* s_col    = (float*)carve((size_t)M * sizeof(float));
    int*   rowstart = (int*)carve((size_t)(M + 1) * sizeof(int));
    int*   tmp_scan = (int*)carve((size_t)M * sizeof(int));
    int*   blocksum = (int*)carve((size_t)256 * sizeof(int));
    int2*  sorted_ce = (int2*)carve((size_t)E * sizeof(int2));    // 6.8MB

    init_kernel<<<512, 256, 0, stream>>>(W, Wt, zero2, 2 * M);

    gemm_mfma_kernel<<<GBLK, 256, 0, stream>>>(x, Wt, hb, a, s_row, s_col, row, deg, M, E);

    const int nb1 = (M + 255) / 256;   // 196
    scan1_kernel<<<nb1, 256, 0, stream>>>(deg, tmp_scan, blocksum, M);
    scan3_kernel<<<nb1, 256, 0, stream>>>(tmp_scan, blocksum, rowstart, M, nb1);
    scatter_kernel<<<(E + 255) / 256, 256, 0, stream>>>(row, col, s_row, s_col,
                                                        rowstart, cursor, sorted_ce, E);

    aggregate_kernel<<<(M + 3) / 4, 256, 0, stream>>>(hb, sorted_ce, rowstart, out, M);
}